// Round 3
// baseline (347.266 us; speedup 1.0000x reference)
//
#include <hip/hip_runtime.h>
#include <hip/hip_bf16.h>

// ---------------------------------------------------------------------------
// GCN 2-layer + BN + tanh. Aggregation via dst-bucketed gather-SpMM (no float
// atomics); both dense GEMMs on bf16 MFMA (fp32 accumulate):
//   gemm1: h = [agg|x] @ [W1rel;W1root] + b1, fused BN-stat block partials
//   gemm2: act = tanh(BN(h)) fused into A-frag load; y2 = act@W2rel,
//          out = act@W2root + b2
// MFMA 16x16x32 bf16 lane maps (m89-verified D; CDNA4 x32 contiguous-k A/B):
//   A: row = lane&15, k = 8*(lane>>4) + i     (i = 0..7)
//   B: col = lane&15, k = 8*(lane>>4) + i     (stored transposed: Wt[n][k])
//   D: col = lane&15, row = 4*(lane>>4) + reg
// ---------------------------------------------------------------------------

#define CAP 32
#define OVF_CAP 131072

typedef __bf16 bf16x8 __attribute__((ext_vector_type(8)));
typedef float f32x4 __attribute__((ext_vector_type(4)));

__device__ __forceinline__ void atomAdd(float* p, float v) { unsafeAtomicAdd(p, v); }

__global__ void detect64_k(const void* __restrict__ ei, int E, int N, int* flag) {
    __shared__ int ok;
    if (threadIdx.x == 0) ok = 1;
    __syncthreads();
    const long long* p = (const long long*)ei;
    int cnt = (E < 1024) ? E : 1024;
    for (int i = threadIdx.x; i < cnt; i += blockDim.x) {
        long long v = p[i];
        if (v < 0 || v >= (long long)N) ok = 0;  // benign race
    }
    __syncthreads();
    if (threadIdx.x == 0) *flag = ok;
}

// Bucket edges by dst: bins[dst*CAP + pos] = {src, w_bits}; overflow -> list.
__global__ __launch_bounds__(256) void fill_k(
    const float* __restrict__ ea, const void* __restrict__ ei,
    const int* __restrict__ flag, int* __restrict__ cnt,
    uint2* __restrict__ bins, int* __restrict__ ovfcnt,
    int4* __restrict__ ovf, int E) {
    int e = blockIdx.x * 256 + threadIdx.x;
    if (e >= E) return;
    const bool is64 = (*flag != 0);
    int src, dst;
    if (is64) {
        const long long* p = (const long long*)ei;
        src = (int)p[e]; dst = (int)p[E + e];
    } else {
        const int* p = (const int*)ei;
        src = p[e]; dst = p[E + e];
    }
    unsigned wb = __float_as_uint(ea[e]);
    int pos = atomicAdd(&cnt[dst], 1);
    if (pos < CAP) {
        bins[(size_t)dst * CAP + pos] = make_uint2((unsigned)src, wb);
    } else {
        int o = atomicAdd(ovfcnt, 1);
        if (o < OVF_CAP) ovf[o] = make_int4(src, dst, (int)wb, 0);
    }
}

// Build transposed bf16 weights: W1t[n][k] (128x128), W2t[n][k] (64x128).
__global__ void cvtw_k(const float* __restrict__ W1rel, const float* __restrict__ W1root,
                       const float* __restrict__ W2rel, const float* __restrict__ W2root,
                       __bf16* __restrict__ W1t, __bf16* __restrict__ W2t) {
    int idx = blockIdx.x * 256 + threadIdx.x;
    if (idx < 128 * 128) {
        int n = idx >> 7, k = idx & 127;
        float v = (k < 64) ? W1rel[k * 128 + n] : W1root[(k - 64) * 128 + n];
        W1t[n * 128 + k] = (__bf16)v;
    } else if (idx < 128 * 128 + 64 * 128) {
        int j = idx - 128 * 128;
        int n = j >> 7, k = j & 127;
        float v = (n < 32) ? W2rel[k * 32 + n] : W2root[k * 32 + (n - 32)];
        W2t[n * 128 + k] = (__bf16)v;
    }
}

// agg[row][0..63] = sum_j w_j * x[src_j][0..63], one wave per row.
__global__ __launch_bounds__(256) void spmm1_k(
    const float* __restrict__ x, const int* __restrict__ cntg,
    const uint2* __restrict__ bins, float* __restrict__ agg, int N) {
    const int lane = threadIdx.x & 63;
    const int row = (blockIdx.x * 256 + threadIdx.x) >> 6;
    if (row >= N) return;
    int cnt = cntg[row]; if (cnt > CAP) cnt = CAP;
    uint2 eg = make_uint2(0u, 0u);
    if (lane < cnt) eg = bins[(size_t)row * CAP + lane];
    float acc = 0.f;
    for (int j = 0; j < cnt; j += 4) {
        int s[4]; float w[4], v[4];
#pragma unroll
        for (int k = 0; k < 4; k++) {
            int idx = j + k;
            bool ok = idx < cnt;
            int ss = __shfl((int)eg.x, idx);
            unsigned wb = (unsigned)__shfl((int)eg.y, idx);
            s[k] = ok ? ss : 0;
            w[k] = ok ? __uint_as_float(wb) : 0.f;
        }
#pragma unroll
        for (int k = 0; k < 4; k++) v[k] = x[(size_t)s[k] * 64 + lane];
#pragma unroll
        for (int k = 0; k < 4; k++) acc = fmaf(w[k], v[k], acc);
    }
    agg[(size_t)row * 64 + lane] = acc;
}

__global__ __launch_bounds__(256) void ovf1_k(
    const float* __restrict__ x, const int* __restrict__ ovfcnt,
    const int4* __restrict__ ovf, float* __restrict__ agg) {
    int n = *ovfcnt; if (n > OVF_CAP) n = OVF_CAP;
    const int lane = threadIdx.x & 63;
    int wid = (blockIdx.x * 256 + threadIdx.x) >> 6;
    int nw = (gridDim.x * 256) >> 6;
    for (int i = wid; i < n; i += nw) {
        int4 t = ovf[i];
        float w = __uint_as_float((unsigned)t.z);
        atomAdd(&agg[(size_t)t.y * 64 + lane], w * x[(size_t)t.x * 64 + lane]);
    }
}

// MFMA gemm1: h = [agg|x] @ W1t^T + b1; per-block BN partial sums (no atomics).
// Block = 4 waves x 16 rows = 64 rows; each wave: 8 col-frags x 4 k-steps.
__global__ __launch_bounds__(256) void gemm1_k(
    const float* __restrict__ agg, const float* __restrict__ x,
    const __bf16* __restrict__ W1t, const float* __restrict__ b1,
    float* __restrict__ h, float* __restrict__ partial, int N) {
    __shared__ float redS[4][128];
    __shared__ float redQ[4][128];
    const int t = threadIdx.x;
    const int lane = t & 63;
    const int w = t >> 6;
    const int rrow = lane & 15;
    const int q = lane >> 4;
    const int row0 = blockIdx.x * 64 + w * 16;
    const int arow = row0 + rrow;
    const int arowc = (arow < N) ? arow : (N - 1);

    f32x4 acc[8];
#pragma unroll
    for (int cb = 0; cb < 8; cb++) {
        acc[cb][0] = 0.f; acc[cb][1] = 0.f; acc[cb][2] = 0.f; acc[cb][3] = 0.f;
    }

#pragma unroll
    for (int ks = 0; ks < 4; ks++) {
        const float* ap = (ks < 2) ? (agg + (size_t)arowc * 64 + ks * 32 + q * 8)
                                   : (x + (size_t)arowc * 64 + (ks - 2) * 32 + q * 8);
        float4 f0 = *(const float4*)ap;
        float4 f1 = *(const float4*)(ap + 4);
        bf16x8 a;
        a[0] = (__bf16)f0.x; a[1] = (__bf16)f0.y; a[2] = (__bf16)f0.z; a[3] = (__bf16)f0.w;
        a[4] = (__bf16)f1.x; a[5] = (__bf16)f1.y; a[6] = (__bf16)f1.z; a[7] = (__bf16)f1.w;
#pragma unroll
        for (int cb = 0; cb < 8; cb++) {
            bf16x8 b = *(const bf16x8*)(W1t + (size_t)(cb * 16 + rrow) * 128 + ks * 32 + q * 8);
            acc[cb] = __builtin_amdgcn_mfma_f32_16x16x32_bf16(a, b, acc[cb], 0, 0, 0);
        }
    }

    float s[8], qs[8];
#pragma unroll
    for (int cb = 0; cb < 8; cb++) {
        const int col = cb * 16 + rrow;
        const float bc = b1[col];
        float ls = 0.f, lq = 0.f;
#pragma unroll
        for (int r = 0; r < 4; r++) {
            int rr = row0 + 4 * q + r;
            if (rr < N) {
                float v = acc[cb][r] + bc;
                h[(size_t)rr * 128 + col] = v;
                ls += v; lq += v * v;
            }
        }
        s[cb] = ls; qs[cb] = lq;
    }
#pragma unroll
    for (int cb = 0; cb < 8; cb++) {
        s[cb] += __shfl_xor(s[cb], 16);  s[cb] += __shfl_xor(s[cb], 32);
        qs[cb] += __shfl_xor(qs[cb], 16); qs[cb] += __shfl_xor(qs[cb], 32);
    }
    if (q == 0) {
#pragma unroll
        for (int cb = 0; cb < 8; cb++) {
            redS[w][cb * 16 + rrow] = s[cb];
            redQ[w][cb * 16 + rrow] = qs[cb];
        }
    }
    __syncthreads();
    if (t < 128) {
        partial[(size_t)blockIdx.x * 256 + t] =
            redS[0][t] + redS[1][t] + redS[2][t] + redS[3][t];
    } else {
        int c = t - 128;
        partial[(size_t)blockIdx.x * 256 + t] =
            redQ[0][c] + redQ[1][c] + redQ[2][c] + redQ[3][c];
    }
}

// Reduce per-block BN partials -> scale/shift.
__global__ void bnfinal_k(const float* __restrict__ partial,
                          const float* __restrict__ gamma, const float* __restrict__ beta,
                          float* __restrict__ scale, float* __restrict__ shift,
                          int nblk, int N) {
    __shared__ float red[256];
    int t = threadIdx.x;  // 256
    float a = 0.f;
    for (int b = 0; b < nblk; b++) a += partial[(size_t)b * 256 + t];
    red[t] = a;
    __syncthreads();
    if (t < 128) {
        float inv = 1.0f / (float)N;
        float mean = red[t] * inv;
        float var = red[t + 128] * inv - mean * mean;
        if (var < 0.f) var = 0.f;
        float sc = gamma[t] * rsqrtf(var + 1e-5f);
        scale[t] = sc;
        shift[t] = beta[t] - mean * sc;
    }
}

// MFMA gemm2: act = tanh(h*scale+shift) fused into A-frag; cols 0..31 -> y2,
// cols 32..63 -> out (+b2).
__global__ __launch_bounds__(256) void gemm2_k(
    const float* __restrict__ h, const float* __restrict__ scale,
    const float* __restrict__ shift, const __bf16* __restrict__ W2t,
    const float* __restrict__ b2, float* __restrict__ y2,
    float* __restrict__ out, int N) {
    const int t = threadIdx.x;
    const int lane = t & 63;
    const int w = t >> 6;
    const int rrow = lane & 15;
    const int q = lane >> 4;
    const int row0 = blockIdx.x * 64 + w * 16;
    const int arow = row0 + rrow;
    const int arowc = (arow < N) ? arow : (N - 1);

    f32x4 acc[4];
#pragma unroll
    for (int cb = 0; cb < 4; cb++) {
        acc[cb][0] = 0.f; acc[cb][1] = 0.f; acc[cb][2] = 0.f; acc[cb][3] = 0.f;
    }

#pragma unroll
    for (int ks = 0; ks < 4; ks++) {
        const int k0 = ks * 32 + q * 8;
        float4 f0 = *(const float4*)(h + (size_t)arowc * 128 + k0);
        float4 f1 = *(const float4*)(h + (size_t)arowc * 128 + k0 + 4);
        float4 sc0 = *(const float4*)(scale + k0);
        float4 sc1 = *(const float4*)(scale + k0 + 4);
        float4 sh0 = *(const float4*)(shift + k0);
        float4 sh1 = *(const float4*)(shift + k0 + 4);
        bf16x8 a;
        a[0] = (__bf16)tanhf(fmaf(f0.x, sc0.x, sh0.x));
        a[1] = (__bf16)tanhf(fmaf(f0.y, sc0.y, sh0.y));
        a[2] = (__bf16)tanhf(fmaf(f0.z, sc0.z, sh0.z));
        a[3] = (__bf16)tanhf(fmaf(f0.w, sc0.w, sh0.w));
        a[4] = (__bf16)tanhf(fmaf(f1.x, sc1.x, sh1.x));
        a[5] = (__bf16)tanhf(fmaf(f1.y, sc1.y, sh1.y));
        a[6] = (__bf16)tanhf(fmaf(f1.z, sc1.z, sh1.z));
        a[7] = (__bf16)tanhf(fmaf(f1.w, sc1.w, sh1.w));
#pragma unroll
        for (int cb = 0; cb < 4; cb++) {
            bf16x8 b = *(const bf16x8*)(W2t + (size_t)(cb * 16 + rrow) * 128 + k0);
            acc[cb] = __builtin_amdgcn_mfma_f32_16x16x32_bf16(a, b, acc[cb], 0, 0, 0);
        }
    }

#pragma unroll
    for (int cb = 0; cb < 4; cb++) {
        const int col = cb * 16 + rrow;
#pragma unroll
        for (int r = 0; r < 4; r++) {
            int rr = row0 + 4 * q + r;
            if (rr < N) {
                if (col < 32) y2[(size_t)rr * 32 + col] = acc[cb][r];
                else          out[(size_t)rr * 32 + (col - 32)] = acc[cb][r] + b2[col - 32];
            }
        }
    }
}

// out[row][0..31] += sum_j w_j * y2[src_j][0..31], one wave per row.
__global__ __launch_bounds__(256) void spmm2_k(
    const float* __restrict__ y2, const int* __restrict__ cntg,
    const uint2* __restrict__ bins, float* __restrict__ out, int N) {
    const int lane = threadIdx.x & 63;
    const int f = lane & 31;
    const int sub = lane >> 5;
    const int row = (blockIdx.x * 256 + threadIdx.x) >> 6;
    if (row >= N) return;
    int cnt = cntg[row]; if (cnt > CAP) cnt = CAP;
    uint2 eg = make_uint2(0u, 0u);
    if (lane < cnt) eg = bins[(size_t)row * CAP + lane];
    float acc = 0.f;
    for (int j = 0; j < cnt; j += 4) {
        int s[2]; float w[2], v[2];
#pragma unroll
        for (int k = 0; k < 2; k++) {
            int idx = j + 2 * k + sub;
            bool ok = idx < cnt;
            int ss = __shfl((int)eg.x, idx);
            unsigned wb = (unsigned)__shfl((int)eg.y, idx);
            s[k] = ok ? ss : 0;
            w[k] = ok ? __uint_as_float(wb) : 0.f;
        }
#pragma unroll
        for (int k = 0; k < 2; k++) v[k] = y2[(size_t)s[k] * 32 + f];
#pragma unroll
        for (int k = 0; k < 2; k++) acc = fmaf(w[k], v[k], acc);
    }
    acc += __shfl_xor(acc, 32);
    if (sub == 0) {
        float* p = &out[(size_t)row * 32 + f];
        *p = *p + acc;
    }
}

__global__ __launch_bounds__(256) void ovf2_k(
    const float* __restrict__ y2, const int* __restrict__ ovfcnt,
    const int4* __restrict__ ovf, float* __restrict__ out) {
    int n = *ovfcnt; if (n > OVF_CAP) n = OVF_CAP;
    const int lane = threadIdx.x & 63;
    const int f = lane & 31;
    int wid = (blockIdx.x * 256 + threadIdx.x) >> 6;
    int nw = (gridDim.x * 256) >> 6;
    for (int i = wid; i < n; i += nw) {
        int4 t = ovf[i];
        if (lane < 32) {
            float w = __uint_as_float((unsigned)t.z);
            atomAdd(&out[(size_t)t.y * 32 + f], w * y2[(size_t)t.x * 32 + f]);
        }
    }
}

extern "C" void kernel_launch(void* const* d_in, const int* in_sizes, int n_in,
                              void* d_out, int out_size, void* d_ws, size_t ws_size,
                              hipStream_t stream) {
    const float* x      = (const float*)d_in[0];
    const float* ea     = (const float*)d_in[1];
    const float* W1rel  = (const float*)d_in[2];
    const float* b1     = (const float*)d_in[3];
    const float* W1root = (const float*)d_in[4];
    const float* gamma  = (const float*)d_in[5];
    const float* beta   = (const float*)d_in[6];
    const float* W2rel  = (const float*)d_in[7];
    const float* b2     = (const float*)d_in[8];
    const float* W2root = (const float*)d_in[9];
    const void*  ei     = d_in[10];

    const int N = in_sizes[0] / 64;   // 50000
    const int E = in_sizes[1];        // 800000
    const int nbg = (N + 63) / 64;    // gemm blocks (64 rows each)

    char* ws = (char*)d_ws;
    size_t off = 0;
    // --- zero-init region (contiguous) ---
    int*   cnt    = (int*)  (ws + off); off += ((size_t)N * 4 + 255) & ~255ull;
    int*   ovfcnt = (int*)  (ws + off); off += 256;
    const size_t zeroBytes = off;
    // --- no-init region ---
    int*    flag    = (int*)   (ws + off); off += 256;
    float*  bnscale = (float*) (ws + off); off += 512;
    float*  bnshift = (float*) (ws + off); off += 512;
    float*  agg1    = (float*) (ws + off); off += (size_t)N * 64 * 4;    // 12.8 MB
    float*  h       = (float*) (ws + off); off += (size_t)N * 128 * 4;   // 25.6 MB
    float*  y2      = (float*) (ws + off); off += (size_t)N * 32 * 4;    // 6.4 MB
    uint2*  bins    = (uint2*) (ws + off); off += (size_t)N * CAP * 8;   // 12.8 MB
    int4*   ovf     = (int4*)  (ws + off); off += (size_t)OVF_CAP * 16;  // 2 MB
    __bf16* W1t     = (__bf16*)(ws + off); off += 128 * 128 * 2;
    __bf16* W2t     = (__bf16*)(ws + off); off += 64 * 128 * 2;
    float*  partial = (float*) (ws + off); off += (size_t)nbg * 256 * 4; // 0.8 MB

    hipMemsetAsync(ws, 0, zeroBytes, stream);
    detect64_k<<<1, 256, 0, stream>>>(ei, E, N, flag);
    fill_k<<<(E + 255) / 256, 256, 0, stream>>>(ea, ei, flag, cnt, bins, ovfcnt, ovf, E);
    cvtw_k<<<96, 256, 0, stream>>>(W1rel, W1root, W2rel, W2root, W1t, W2t);
    const int rowBlocks = (N * 64 + 255) / 256;
    spmm1_k<<<rowBlocks, 256, 0, stream>>>(x, cnt, bins, agg1, N);
    ovf1_k<<<32, 256, 0, stream>>>(x, ovfcnt, ovf, agg1);
    gemm1_k<<<nbg, 256, 0, stream>>>(agg1, x, W1t, b1, h, partial, N);
    bnfinal_k<<<1, 256, 0, stream>>>(partial, gamma, beta, bnscale, bnshift, nbg, N);
    gemm2_k<<<nbg, 256, 0, stream>>>(h, bnscale, bnshift, W2t, b2, y2, (float*)d_out, N);
    spmm2_k<<<rowBlocks, 256, 0, stream>>>(y2, cnt, bins, (float*)d_out, N);
    ovf2_k<<<32, 256, 0, stream>>>(y2, ovfcnt, ovf, (float*)d_out);
}

// Round 4
// 182.143 us; speedup vs baseline: 1.9066x; 1.9066x over previous
//
#include <hip/hip_runtime.h>
#include <hip/hip_bf16.h>

// ---------------------------------------------------------------------------
// GCN 2-layer + BN + tanh. Aggregation via dst-bucketed gather-SpMM (no float
// atomics on the N x F maps); both dense GEMMs on bf16 MFMA (fp32 accumulate):
//   gemm1: h = [agg|x] @ [W1rel;W1root] + b1, BN partials -> 256 f32 atomics
//   gemm2: act = tanh(BN(h)) fused into A-frag load; y2 = act@W2rel,
//          out = act@W2root + b2
// MFMA 16x16x32 bf16 lane maps (m89-verified D):
//   A: row = lane&15, k = 8*(lane>>4) + i     (i = 0..7)
//   B: col = lane&15, k = 8*(lane>>4) + i     (stored transposed: Wt[n][k])
//   D: col = lane&15, row = 4*(lane>>4) + reg
// ---------------------------------------------------------------------------

#define CAP 32
#define OVF_CAP 131072

typedef __bf16 bf16x8 __attribute__((ext_vector_type(8)));
typedef float f32x4 __attribute__((ext_vector_type(4)));

__device__ __forceinline__ void atomAdd(float* p, float v) { unsafeAtomicAdd(p, v); }

__global__ void detect64_k(const void* __restrict__ ei, int E, int N, int* flag) {
    __shared__ int ok;
    if (threadIdx.x == 0) ok = 1;
    __syncthreads();
    const long long* p = (const long long*)ei;
    int cnt = (E < 1024) ? E : 1024;
    for (int i = threadIdx.x; i < cnt; i += blockDim.x) {
        long long v = p[i];
        if (v < 0 || v >= (long long)N) ok = 0;  // benign race
    }
    __syncthreads();
    if (threadIdx.x == 0) *flag = ok;
}

// Bucket edges by dst: bins[dst*CAP + pos] = {src, w_bits}; overflow -> list.
__global__ __launch_bounds__(256) void fill_k(
    const float* __restrict__ ea, const void* __restrict__ ei,
    const int* __restrict__ flag, int* __restrict__ cnt,
    uint2* __restrict__ bins, int* __restrict__ ovfcnt,
    int4* __restrict__ ovf, int E) {
    int e = blockIdx.x * 256 + threadIdx.x;
    if (e >= E) return;
    const bool is64 = (*flag != 0);
    int src, dst;
    if (is64) {
        const long long* p = (const long long*)ei;
        src = (int)p[e]; dst = (int)p[E + e];
    } else {
        const int* p = (const int*)ei;
        src = p[e]; dst = p[E + e];
    }
    unsigned wb = __float_as_uint(ea[e]);
    int pos = atomicAdd(&cnt[dst], 1);
    if (pos < CAP) {
        bins[(size_t)dst * CAP + pos] = make_uint2((unsigned)src, wb);
    } else {
        int o = atomicAdd(ovfcnt, 1);
        if (o < OVF_CAP) ovf[o] = make_int4(src, dst, (int)wb, 0);
    }
}

// Build transposed bf16 weights: W1t[n][k] (128x128), W2t[n][k] (64x128).
__global__ void cvtw_k(const float* __restrict__ W1rel, const float* __restrict__ W1root,
                       const float* __restrict__ W2rel, const float* __restrict__ W2root,
                       __bf16* __restrict__ W1t, __bf16* __restrict__ W2t) {
    int idx = blockIdx.x * 256 + threadIdx.x;
    if (idx < 128 * 128) {
        int n = idx >> 7, k = idx & 127;
        float v = (k < 64) ? W1rel[k * 128 + n] : W1root[(k - 64) * 128 + n];
        W1t[n * 128 + k] = (__bf16)v;
    } else if (idx < 128 * 128 + 64 * 128) {
        int j = idx - 128 * 128;
        int n = j >> 7, k = j & 127;
        float v = (n < 32) ? W2rel[k * 32 + n] : W2root[k * 32 + (n - 32)];
        W2t[n * 128 + k] = (__bf16)v;
    }
}

// agg[row][0..63] = sum_j w_j * x[src_j][0..63], one wave per row.
__global__ __launch_bounds__(256) void spmm1_k(
    const float* __restrict__ x, const int* __restrict__ cntg,
    const uint2* __restrict__ bins, float* __restrict__ agg, int N) {
    const int lane = threadIdx.x & 63;
    const int row = (blockIdx.x * 256 + threadIdx.x) >> 6;
    if (row >= N) return;
    int cnt = cntg[row]; if (cnt > CAP) cnt = CAP;
    uint2 eg = make_uint2(0u, 0u);
    if (lane < cnt) eg = bins[(size_t)row * CAP + lane];
    float acc = 0.f;
    for (int j = 0; j < cnt; j += 4) {
        int s[4]; float w[4], v[4];
#pragma unroll
        for (int k = 0; k < 4; k++) {
            int idx = j + k;
            bool ok = idx < cnt;
            int ss = __shfl((int)eg.x, idx);
            unsigned wb = (unsigned)__shfl((int)eg.y, idx);
            s[k] = ok ? ss : 0;
            w[k] = ok ? __uint_as_float(wb) : 0.f;
        }
#pragma unroll
        for (int k = 0; k < 4; k++) v[k] = x[(size_t)s[k] * 64 + lane];
#pragma unroll
        for (int k = 0; k < 4; k++) acc = fmaf(w[k], v[k], acc);
    }
    agg[(size_t)row * 64 + lane] = acc;
}

__global__ __launch_bounds__(256) void ovf1_k(
    const float* __restrict__ x, const int* __restrict__ ovfcnt,
    const int4* __restrict__ ovf, float* __restrict__ agg) {
    int n = *ovfcnt; if (n > OVF_CAP) n = OVF_CAP;
    const int lane = threadIdx.x & 63;
    int wid = (blockIdx.x * 256 + threadIdx.x) >> 6;
    int nw = (gridDim.x * 256) >> 6;
    for (int i = wid; i < n; i += nw) {
        int4 t = ovf[i];
        float w = __uint_as_float((unsigned)t.z);
        atomAdd(&agg[(size_t)t.y * 64 + lane], w * x[(size_t)t.x * 64 + lane]);
    }
}

// MFMA gemm1: h = [agg|x] @ W1t^T + b1; BN partials -> 256 f32 atomics.
// Block = 4 waves x 16 rows = 64 rows; each wave: 8 col-frags x 4 k-steps.
__global__ __launch_bounds__(256) void gemm1_k(
    const float* __restrict__ agg, const float* __restrict__ x,
    const __bf16* __restrict__ W1t, const float* __restrict__ b1,
    float* __restrict__ h, float* __restrict__ bnsum, float* __restrict__ bnsq,
    int N) {
    __shared__ float redS[4][128];
    __shared__ float redQ[4][128];
    const int t = threadIdx.x;
    const int lane = t & 63;
    const int w = t >> 6;
    const int rrow = lane & 15;
    const int q = lane >> 4;
    const int row0 = blockIdx.x * 64 + w * 16;
    const int arow = row0 + rrow;
    const int arowc = (arow < N) ? arow : (N - 1);

    f32x4 acc[8];
#pragma unroll
    for (int cb = 0; cb < 8; cb++) {
        acc[cb][0] = 0.f; acc[cb][1] = 0.f; acc[cb][2] = 0.f; acc[cb][3] = 0.f;
    }

#pragma unroll
    for (int ks = 0; ks < 4; ks++) {
        const float* ap = (ks < 2) ? (agg + (size_t)arowc * 64 + ks * 32 + q * 8)
                                   : (x + (size_t)arowc * 64 + (ks - 2) * 32 + q * 8);
        float4 f0 = *(const float4*)ap;
        float4 f1 = *(const float4*)(ap + 4);
        bf16x8 a;
        a[0] = (__bf16)f0.x; a[1] = (__bf16)f0.y; a[2] = (__bf16)f0.z; a[3] = (__bf16)f0.w;
        a[4] = (__bf16)f1.x; a[5] = (__bf16)f1.y; a[6] = (__bf16)f1.z; a[7] = (__bf16)f1.w;
#pragma unroll
        for (int cb = 0; cb < 8; cb++) {
            bf16x8 b = *(const bf16x8*)(W1t + (size_t)(cb * 16 + rrow) * 128 + ks * 32 + q * 8);
            acc[cb] = __builtin_amdgcn_mfma_f32_16x16x32_bf16(a, b, acc[cb], 0, 0, 0);
        }
    }

    float s[8], qs[8];
#pragma unroll
    for (int cb = 0; cb < 8; cb++) {
        const int col = cb * 16 + rrow;
        const float bc = b1[col];
        float ls = 0.f, lq = 0.f;
#pragma unroll
        for (int r = 0; r < 4; r++) {
            int rr = row0 + 4 * q + r;
            if (rr < N) {
                float v = acc[cb][r] + bc;
                h[(size_t)rr * 128 + col] = v;
                ls += v; lq += v * v;
            }
        }
        s[cb] = ls; qs[cb] = lq;
    }
#pragma unroll
    for (int cb = 0; cb < 8; cb++) {
        s[cb] += __shfl_xor(s[cb], 16);  s[cb] += __shfl_xor(s[cb], 32);
        qs[cb] += __shfl_xor(qs[cb], 16); qs[cb] += __shfl_xor(qs[cb], 32);
    }
    if (q == 0) {
#pragma unroll
        for (int cb = 0; cb < 8; cb++) {
            redS[w][cb * 16 + rrow] = s[cb];
            redQ[w][cb * 16 + rrow] = qs[cb];
        }
    }
    __syncthreads();
    if (t < 128) {
        atomAdd(&bnsum[t], redS[0][t] + redS[1][t] + redS[2][t] + redS[3][t]);
    } else {
        int c = t - 128;
        atomAdd(&bnsq[c], redQ[0][c] + redQ[1][c] + redQ[2][c] + redQ[3][c]);
    }
}

__global__ void bnfinal_k(const float* __restrict__ bnsum, const float* __restrict__ bnsq,
                          const float* __restrict__ gamma, const float* __restrict__ beta,
                          float* __restrict__ scale, float* __restrict__ shift, int N) {
    int t = threadIdx.x;  // 128
    float inv = 1.0f / (float)N;
    float mean = bnsum[t] * inv;
    float var = bnsq[t] * inv - mean * mean;
    if (var < 0.f) var = 0.f;
    float sc = gamma[t] * rsqrtf(var + 1e-5f);
    scale[t] = sc;
    shift[t] = beta[t] - mean * sc;
}

// MFMA gemm2: act = tanh(h*scale+shift) fused into A-frag; cols 0..31 -> y2,
// cols 32..63 -> out (+b2).
__global__ __launch_bounds__(256) void gemm2_k(
    const float* __restrict__ h, const float* __restrict__ scale,
    const float* __restrict__ shift, const __bf16* __restrict__ W2t,
    const float* __restrict__ b2, float* __restrict__ y2,
    float* __restrict__ out, int N) {
    const int t = threadIdx.x;
    const int lane = t & 63;
    const int w = t >> 6;
    const int rrow = lane & 15;
    const int q = lane >> 4;
    const int row0 = blockIdx.x * 64 + w * 16;
    const int arow = row0 + rrow;
    const int arowc = (arow < N) ? arow : (N - 1);

    f32x4 acc[4];
#pragma unroll
    for (int cb = 0; cb < 4; cb++) {
        acc[cb][0] = 0.f; acc[cb][1] = 0.f; acc[cb][2] = 0.f; acc[cb][3] = 0.f;
    }

#pragma unroll
    for (int ks = 0; ks < 4; ks++) {
        const int k0 = ks * 32 + q * 8;
        float4 f0 = *(const float4*)(h + (size_t)arowc * 128 + k0);
        float4 f1 = *(const float4*)(h + (size_t)arowc * 128 + k0 + 4);
        float4 sc0 = *(const float4*)(scale + k0);
        float4 sc1 = *(const float4*)(scale + k0 + 4);
        float4 sh0 = *(const float4*)(shift + k0);
        float4 sh1 = *(const float4*)(shift + k0 + 4);
        bf16x8 a;
        a[0] = (__bf16)tanhf(fmaf(f0.x, sc0.x, sh0.x));
        a[1] = (__bf16)tanhf(fmaf(f0.y, sc0.y, sh0.y));
        a[2] = (__bf16)tanhf(fmaf(f0.z, sc0.z, sh0.z));
        a[3] = (__bf16)tanhf(fmaf(f0.w, sc0.w, sh0.w));
        a[4] = (__bf16)tanhf(fmaf(f1.x, sc1.x, sh1.x));
        a[5] = (__bf16)tanhf(fmaf(f1.y, sc1.y, sh1.y));
        a[6] = (__bf16)tanhf(fmaf(f1.z, sc1.z, sh1.z));
        a[7] = (__bf16)tanhf(fmaf(f1.w, sc1.w, sh1.w));
#pragma unroll
        for (int cb = 0; cb < 4; cb++) {
            bf16x8 b = *(const bf16x8*)(W2t + (size_t)(cb * 16 + rrow) * 128 + k0);
            acc[cb] = __builtin_amdgcn_mfma_f32_16x16x32_bf16(a, b, acc[cb], 0, 0, 0);
        }
    }

#pragma unroll
    for (int cb = 0; cb < 4; cb++) {
        const int col = cb * 16 + rrow;
#pragma unroll
        for (int r = 0; r < 4; r++) {
            int rr = row0 + 4 * q + r;
            if (rr < N) {
                if (col < 32) y2[(size_t)rr * 32 + col] = acc[cb][r];
                else          out[(size_t)rr * 32 + (col - 32)] = acc[cb][r] + b2[col - 32];
            }
        }
    }
}

// out[row][0..31] += sum_j w_j * y2[src_j][0..31], one wave per row.
__global__ __launch_bounds__(256) void spmm2_k(
    const float* __restrict__ y2, const int* __restrict__ cntg,
    const uint2* __restrict__ bins, float* __restrict__ out, int N) {
    const int lane = threadIdx.x & 63;
    const int f = lane & 31;
    const int sub = lane >> 5;
    const int row = (blockIdx.x * 256 + threadIdx.x) >> 6;
    if (row >= N) return;
    int cnt = cntg[row]; if (cnt > CAP) cnt = CAP;
    uint2 eg = make_uint2(0u, 0u);
    if (lane < cnt) eg = bins[(size_t)row * CAP + lane];
    float acc = 0.f;
    for (int j = 0; j < cnt; j += 4) {
        int s[2]; float w[2], v[2];
#pragma unroll
        for (int k = 0; k < 2; k++) {
            int idx = j + 2 * k + sub;
            bool ok = idx < cnt;
            int ss = __shfl((int)eg.x, idx);
            unsigned wb = (unsigned)__shfl((int)eg.y, idx);
            s[k] = ok ? ss : 0;
            w[k] = ok ? __uint_as_float(wb) : 0.f;
        }
#pragma unroll
        for (int k = 0; k < 2; k++) v[k] = y2[(size_t)s[k] * 32 + f];
#pragma unroll
        for (int k = 0; k < 2; k++) acc = fmaf(w[k], v[k], acc);
    }
    acc += __shfl_xor(acc, 32);
    if (sub == 0) {
        float* p = &out[(size_t)row * 32 + f];
        *p = *p + acc;
    }
}

__global__ __launch_bounds__(256) void ovf2_k(
    const float* __restrict__ y2, const int* __restrict__ ovfcnt,
    const int4* __restrict__ ovf, float* __restrict__ out) {
    int n = *ovfcnt; if (n > OVF_CAP) n = OVF_CAP;
    const int lane = threadIdx.x & 63;
    const int f = lane & 31;
    int wid = (blockIdx.x * 256 + threadIdx.x) >> 6;
    int nw = (gridDim.x * 256) >> 6;
    for (int i = wid; i < n; i += nw) {
        int4 t = ovf[i];
        if (lane < 32) {
            float w = __uint_as_float((unsigned)t.z);
            atomAdd(&out[(size_t)t.y * 32 + f], w * y2[(size_t)t.x * 32 + f]);
        }
    }
}

extern "C" void kernel_launch(void* const* d_in, const int* in_sizes, int n_in,
                              void* d_out, int out_size, void* d_ws, size_t ws_size,
                              hipStream_t stream) {
    const float* x      = (const float*)d_in[0];
    const float* ea     = (const float*)d_in[1];
    const float* W1rel  = (const float*)d_in[2];
    const float* b1     = (const float*)d_in[3];
    const float* W1root = (const float*)d_in[4];
    const float* gamma  = (const float*)d_in[5];
    const float* beta   = (const float*)d_in[6];
    const float* W2rel  = (const float*)d_in[7];
    const float* b2     = (const float*)d_in[8];
    const float* W2root = (const float*)d_in[9];
    const void*  ei     = d_in[10];

    const int N = in_sizes[0] / 64;   // 50000
    const int E = in_sizes[1];        // 800000
    const int nbg = (N + 63) / 64;    // gemm blocks (64 rows each)

    char* ws = (char*)d_ws;
    size_t off = 0;
    // --- zero-init region (contiguous) ---
    int*   cnt    = (int*)  (ws + off); off += ((size_t)N * 4 + 255) & ~255ull;
    int*   ovfcnt = (int*)  (ws + off); off += 256;
    float* bnsum  = (float*)(ws + off); off += 512;
    float* bnsq   = (float*)(ws + off); off += 512;
    const size_t zeroBytes = off;
    // --- no-init region ---
    int*    flag    = (int*)   (ws + off); off += 256;
    float*  bnscale = (float*) (ws + off); off += 512;
    float*  bnshift = (float*) (ws + off); off += 512;
    float*  agg1    = (float*) (ws + off); off += (size_t)N * 64 * 4;    // 12.8 MB
    float*  h       = (float*) (ws + off); off += (size_t)N * 128 * 4;   // 25.6 MB
    float*  y2      = (float*) (ws + off); off += (size_t)N * 32 * 4;    // 6.4 MB
    uint2*  bins    = (uint2*) (ws + off); off += (size_t)N * CAP * 8;   // 12.8 MB
    int4*   ovf     = (int4*)  (ws + off); off += (size_t)OVF_CAP * 16;  // 2 MB
    __bf16* W1t     = (__bf16*)(ws + off); off += 128 * 128 * 2;
    __bf16* W2t     = (__bf16*)(ws + off); off += 64 * 128 * 2;

    hipMemsetAsync(ws, 0, zeroBytes, stream);
    detect64_k<<<1, 256, 0, stream>>>(ei, E, N, flag);
    fill_k<<<(E + 255) / 256, 256, 0, stream>>>(ea, ei, flag, cnt, bins, ovfcnt, ovf, E);
    cvtw_k<<<96, 256, 0, stream>>>(W1rel, W1root, W2rel, W2root, W1t, W2t);
    const int rowBlocks = (N * 64 + 255) / 256;
    spmm1_k<<<rowBlocks, 256, 0, stream>>>(x, cnt, bins, agg1, N);
    ovf1_k<<<32, 256, 0, stream>>>(x, ovfcnt, ovf, agg1);
    gemm1_k<<<nbg, 256, 0, stream>>>(agg1, x, W1t, b1, h, bnsum, bnsq, N);
    bnfinal_k<<<1, 128, 0, stream>>>(bnsum, bnsq, gamma, beta, bnscale, bnshift, N);
    gemm2_k<<<nbg, 256, 0, stream>>>(h, bnscale, bnshift, W2t, b2, y2, (float*)d_out, N);
    spmm2_k<<<rowBlocks, 256, 0, stream>>>(y2, cnt, bins, (float*)d_out, N);
    ovf2_k<<<32, 256, 0, stream>>>(y2, ovfcnt, ovf, (float*)d_out);
}

// Round 5
// 171.047 us; speedup vs baseline: 2.0302x; 1.0649x over previous
//
#include <hip/hip_runtime.h>
#include <hip/hip_bf16.h>

// ---------------------------------------------------------------------------
// GCN 2-layer + BN + tanh. Aggregation via dst-bucketed gather-SpMM (no float
// atomics on the N x F maps); both dense GEMMs on bf16 MFMA (fp32 accumulate):
//   gemm1: h = [agg|x] @ [W1rel;W1root] + b1, BN partials -> 256 f32 atomics
//   gemm2: act = tanh(BN(h)) fused into A-frag load; y2 = act@W2rel,
//          out = act@W2root + b2
// fill_k: ILP=4 edges/thread (4 independent atomic+store chains) + in-kernel
// dtype detect (wave-0 ballot) to kill the serializing detect launch.
// MFMA 16x16x32 bf16 lane maps (m89-verified D):
//   A: row = lane&15, k = 8*(lane>>4) + i     (i = 0..7)
//   B: col = lane&15, k = 8*(lane>>4) + i     (stored transposed: Wt[n][k])
//   D: col = lane&15, row = 4*(lane>>4) + reg
// ---------------------------------------------------------------------------

#define CAP 32
#define OVF_CAP 131072

typedef __bf16 bf16x8 __attribute__((ext_vector_type(8)));
typedef float f32x4 __attribute__((ext_vector_type(4)));

__device__ __forceinline__ void atomAdd(float* p, float v) { unsafeAtomicAdd(p, v); }

// Per-block edge_index dtype detect: read 16 leading int64 values; int32 data
// read as int64 pairs random idx with a high word that is nonzero w.p.
// 1-2e-5 per element -> P(misdetect) ~ (2e-5)^16 ~ 0.
__device__ __forceinline__ bool detect_is64(const void* ei, int N, int* s_flag) {
    if (threadIdx.x < 64) {
        const long long* p = (const long long*)ei;
        long long v = p[threadIdx.x & 15];
        int ok = (v >= 0 && v < (long long)N);
        unsigned long long m = __ballot(ok);
        if (threadIdx.x == 0) *s_flag = (~m == 0ull) ? 1 : 0;
    }
    __syncthreads();
    return *s_flag != 0;
}

// Bucket edges by dst: bins[dst*CAP + pos] = {src, w_bits}; overflow -> list.
// 4 edges per thread for latency hiding.
__global__ __launch_bounds__(256) void fill_k(
    const float* __restrict__ ea, const void* __restrict__ ei,
    int* __restrict__ cnt, uint2* __restrict__ bins,
    int* __restrict__ ovfcnt, int4* __restrict__ ovf, int E, int N) {
    __shared__ int s_flag;
    const bool is64 = detect_is64(ei, N, &s_flag);

    int t4 = (blockIdx.x * 256 + threadIdx.x) * 4;
    if (t4 >= E) return;
    int n = E - t4; if (n > 4) n = 4;

    int srcs[4], dsts[4];
    float wv[4];
    if (is64) {
        const long long* p = (const long long*)ei;
        if (n == 4) {
            int4 a0 = *(const int4*)(p + t4);
            int4 a1 = *(const int4*)(p + t4 + 2);
            int4 b0 = *(const int4*)(p + E + t4);
            int4 b1 = *(const int4*)(p + E + t4 + 2);
            srcs[0] = a0.x; srcs[1] = a0.z; srcs[2] = a1.x; srcs[3] = a1.z;
            dsts[0] = b0.x; dsts[1] = b0.z; dsts[2] = b1.x; dsts[3] = b1.z;
        } else {
            for (int k = 0; k < n; k++) { srcs[k] = (int)p[t4 + k]; dsts[k] = (int)p[E + t4 + k]; }
        }
    } else {
        const int* p = (const int*)ei;
        if (n == 4) {
            int4 a = *(const int4*)(p + t4);
            int4 b = *(const int4*)(p + E + t4);
            srcs[0] = a.x; srcs[1] = a.y; srcs[2] = a.z; srcs[3] = a.w;
            dsts[0] = b.x; dsts[1] = b.y; dsts[2] = b.z; dsts[3] = b.w;
        } else {
            for (int k = 0; k < n; k++) { srcs[k] = p[t4 + k]; dsts[k] = p[E + t4 + k]; }
        }
    }
    if (n == 4) {
        float4 w = *(const float4*)(ea + t4);
        wv[0] = w.x; wv[1] = w.y; wv[2] = w.z; wv[3] = w.w;
    } else {
        for (int k = 0; k < n; k++) wv[k] = ea[t4 + k];
    }

    int pos[4];
#pragma unroll
    for (int k = 0; k < 4; k++)
        if (k < n) pos[k] = atomicAdd(&cnt[dsts[k]], 1);
#pragma unroll
    for (int k = 0; k < 4; k++) {
        if (k < n) {
            if (pos[k] < CAP) {
                bins[(size_t)dsts[k] * CAP + pos[k]] =
                    make_uint2((unsigned)srcs[k], __float_as_uint(wv[k]));
            } else {
                int o = atomicAdd(ovfcnt, 1);
                if (o < OVF_CAP) ovf[o] = make_int4(srcs[k], dsts[k], (int)__float_as_uint(wv[k]), 0);
            }
        }
    }
}

// Build transposed bf16 weights: W1t[n][k] (128x128), W2t[n][k] (64x128).
__global__ void cvtw_k(const float* __restrict__ W1rel, const float* __restrict__ W1root,
                       const float* __restrict__ W2rel, const float* __restrict__ W2root,
                       __bf16* __restrict__ W1t, __bf16* __restrict__ W2t) {
    int idx = blockIdx.x * 256 + threadIdx.x;
    if (idx < 128 * 128) {
        int n = idx >> 7, k = idx & 127;
        float v = (k < 64) ? W1rel[k * 128 + n] : W1root[(k - 64) * 128 + n];
        W1t[n * 128 + k] = (__bf16)v;
    } else if (idx < 128 * 128 + 64 * 128) {
        int j = idx - 128 * 128;
        int n = j >> 7, k = j & 127;
        float v = (n < 32) ? W2rel[k * 32 + n] : W2root[k * 32 + (n - 32)];
        W2t[n * 128 + k] = (__bf16)v;
    }
}

// agg[row][0..63] = sum_j w_j * x[src_j][0..63], one wave per row.
__global__ __launch_bounds__(256) void spmm1_k(
    const float* __restrict__ x, const int* __restrict__ cntg,
    const uint2* __restrict__ bins, float* __restrict__ agg, int N) {
    const int lane = threadIdx.x & 63;
    const int row = (blockIdx.x * 256 + threadIdx.x) >> 6;
    if (row >= N) return;
    int cnt = cntg[row]; if (cnt > CAP) cnt = CAP;
    uint2 eg = make_uint2(0u, 0u);
    if (lane < cnt) eg = bins[(size_t)row * CAP + lane];
    float acc = 0.f;
    for (int j = 0; j < cnt; j += 4) {
        int s[4]; float w[4], v[4];
#pragma unroll
        for (int k = 0; k < 4; k++) {
            int idx = j + k;
            bool ok = idx < cnt;
            int ss = __shfl((int)eg.x, idx);
            unsigned wb = (unsigned)__shfl((int)eg.y, idx);
            s[k] = ok ? ss : 0;
            w[k] = ok ? __uint_as_float(wb) : 0.f;
        }
#pragma unroll
        for (int k = 0; k < 4; k++) v[k] = x[(size_t)s[k] * 64 + lane];
#pragma unroll
        for (int k = 0; k < 4; k++) acc = fmaf(w[k], v[k], acc);
    }
    agg[(size_t)row * 64 + lane] = acc;
}

__global__ __launch_bounds__(256) void ovf1_k(
    const float* __restrict__ x, const int* __restrict__ ovfcnt,
    const int4* __restrict__ ovf, float* __restrict__ agg) {
    int n = *ovfcnt; if (n > OVF_CAP) n = OVF_CAP;
    const int lane = threadIdx.x & 63;
    int wid = (blockIdx.x * 256 + threadIdx.x) >> 6;
    int nw = (gridDim.x * 256) >> 6;
    for (int i = wid; i < n; i += nw) {
        int4 t = ovf[i];
        float w = __uint_as_float((unsigned)t.z);
        atomAdd(&agg[(size_t)t.y * 64 + lane], w * x[(size_t)t.x * 64 + lane]);
    }
}

// MFMA gemm1: h = [agg|x] @ W1t^T + b1; BN partials -> 256 f32 atomics.
// Block = 4 waves x 16 rows = 64 rows; each wave: 8 col-frags x 4 k-steps.
__global__ __launch_bounds__(256) void gemm1_k(
    const float* __restrict__ agg, const float* __restrict__ x,
    const __bf16* __restrict__ W1t, const float* __restrict__ b1,
    float* __restrict__ h, float* __restrict__ bnsum, float* __restrict__ bnsq,
    int N) {
    __shared__ float redS[4][128];
    __shared__ float redQ[4][128];
    const int t = threadIdx.x;
    const int lane = t & 63;
    const int w = t >> 6;
    const int rrow = lane & 15;
    const int q = lane >> 4;
    const int row0 = blockIdx.x * 64 + w * 16;
    const int arow = row0 + rrow;
    const int arowc = (arow < N) ? arow : (N - 1);

    f32x4 acc[8];
#pragma unroll
    for (int cb = 0; cb < 8; cb++) {
        acc[cb][0] = 0.f; acc[cb][1] = 0.f; acc[cb][2] = 0.f; acc[cb][3] = 0.f;
    }

#pragma unroll
    for (int ks = 0; ks < 4; ks++) {
        const float* ap = (ks < 2) ? (agg + (size_t)arowc * 64 + ks * 32 + q * 8)
                                   : (x + (size_t)arowc * 64 + (ks - 2) * 32 + q * 8);
        float4 f0 = *(const float4*)ap;
        float4 f1 = *(const float4*)(ap + 4);
        bf16x8 a;
        a[0] = (__bf16)f0.x; a[1] = (__bf16)f0.y; a[2] = (__bf16)f0.z; a[3] = (__bf16)f0.w;
        a[4] = (__bf16)f1.x; a[5] = (__bf16)f1.y; a[6] = (__bf16)f1.z; a[7] = (__bf16)f1.w;
#pragma unroll
        for (int cb = 0; cb < 8; cb++) {
            bf16x8 b = *(const bf16x8*)(W1t + (size_t)(cb * 16 + rrow) * 128 + ks * 32 + q * 8);
            acc[cb] = __builtin_amdgcn_mfma_f32_16x16x32_bf16(a, b, acc[cb], 0, 0, 0);
        }
    }

    float s[8], qs[8];
#pragma unroll
    for (int cb = 0; cb < 8; cb++) {
        const int col = cb * 16 + rrow;
        const float bc = b1[col];
        float ls = 0.f, lq = 0.f;
#pragma unroll
        for (int r = 0; r < 4; r++) {
            int rr = row0 + 4 * q + r;
            if (rr < N) {
                float v = acc[cb][r] + bc;
                h[(size_t)rr * 128 + col] = v;
                ls += v; lq += v * v;
            }
        }
        s[cb] = ls; qs[cb] = lq;
    }
#pragma unroll
    for (int cb = 0; cb < 8; cb++) {
        s[cb] += __shfl_xor(s[cb], 16);  s[cb] += __shfl_xor(s[cb], 32);
        qs[cb] += __shfl_xor(qs[cb], 16); qs[cb] += __shfl_xor(qs[cb], 32);
    }
    if (q == 0) {
#pragma unroll
        for (int cb = 0; cb < 8; cb++) {
            redS[w][cb * 16 + rrow] = s[cb];
            redQ[w][cb * 16 + rrow] = qs[cb];
        }
    }
    __syncthreads();
    if (t < 128) {
        atomAdd(&bnsum[t], redS[0][t] + redS[1][t] + redS[2][t] + redS[3][t]);
    } else {
        int c = t - 128;
        atomAdd(&bnsq[c], redQ[0][c] + redQ[1][c] + redQ[2][c] + redQ[3][c]);
    }
}

__global__ void bnfinal_k(const float* __restrict__ bnsum, const float* __restrict__ bnsq,
                          const float* __restrict__ gamma, const float* __restrict__ beta,
                          float* __restrict__ scale, float* __restrict__ shift, int N) {
    int t = threadIdx.x;  // 128
    float inv = 1.0f / (float)N;
    float mean = bnsum[t] * inv;
    float var = bnsq[t] * inv - mean * mean;
    if (var < 0.f) var = 0.f;
    float sc = gamma[t] * rsqrtf(var + 1e-5f);
    scale[t] = sc;
    shift[t] = beta[t] - mean * sc;
}

// MFMA gemm2: act = tanh(h*scale+shift) fused into A-frag; cols 0..31 -> y2,
// cols 32..63 -> out (+b2).
__global__ __launch_bounds__(256) void gemm2_k(
    const float* __restrict__ h, const float* __restrict__ scale,
    const float* __restrict__ shift, const __bf16* __restrict__ W2t,
    const float* __restrict__ b2, float* __restrict__ y2,
    float* __restrict__ out, int N) {
    const int t = threadIdx.x;
    const int lane = t & 63;
    const int w = t >> 6;
    const int rrow = lane & 15;
    const int q = lane >> 4;
    const int row0 = blockIdx.x * 64 + w * 16;
    const int arow = row0 + rrow;
    const int arowc = (arow < N) ? arow : (N - 1);

    f32x4 acc[4];
#pragma unroll
    for (int cb = 0; cb < 4; cb++) {
        acc[cb][0] = 0.f; acc[cb][1] = 0.f; acc[cb][2] = 0.f; acc[cb][3] = 0.f;
    }

#pragma unroll
    for (int ks = 0; ks < 4; ks++) {
        const int k0 = ks * 32 + q * 8;
        float4 f0 = *(const float4*)(h + (size_t)arowc * 128 + k0);
        float4 f1 = *(const float4*)(h + (size_t)arowc * 128 + k0 + 4);
        float4 sc0 = *(const float4*)(scale + k0);
        float4 sc1 = *(const float4*)(scale + k0 + 4);
        float4 sh0 = *(const float4*)(shift + k0);
        float4 sh1 = *(const float4*)(shift + k0 + 4);
        bf16x8 a;
        a[0] = (__bf16)tanhf(fmaf(f0.x, sc0.x, sh0.x));
        a[1] = (__bf16)tanhf(fmaf(f0.y, sc0.y, sh0.y));
        a[2] = (__bf16)tanhf(fmaf(f0.z, sc0.z, sh0.z));
        a[3] = (__bf16)tanhf(fmaf(f0.w, sc0.w, sh0.w));
        a[4] = (__bf16)tanhf(fmaf(f1.x, sc1.x, sh1.x));
        a[5] = (__bf16)tanhf(fmaf(f1.y, sc1.y, sh1.y));
        a[6] = (__bf16)tanhf(fmaf(f1.z, sc1.z, sh1.z));
        a[7] = (__bf16)tanhf(fmaf(f1.w, sc1.w, sh1.w));
#pragma unroll
        for (int cb = 0; cb < 4; cb++) {
            bf16x8 b = *(const bf16x8*)(W2t + (size_t)(cb * 16 + rrow) * 128 + k0);
            acc[cb] = __builtin_amdgcn_mfma_f32_16x16x32_bf16(a, b, acc[cb], 0, 0, 0);
        }
    }

#pragma unroll
    for (int cb = 0; cb < 4; cb++) {
        const int col = cb * 16 + rrow;
#pragma unroll
        for (int r = 0; r < 4; r++) {
            int rr = row0 + 4 * q + r;
            if (rr < N) {
                if (col < 32) y2[(size_t)rr * 32 + col] = acc[cb][r];
                else          out[(size_t)rr * 32 + (col - 32)] = acc[cb][r] + b2[col - 32];
            }
        }
    }
}

// out[row][0..31] += sum_j w_j * y2[src_j][0..31], one wave per row.
__global__ __launch_bounds__(256) void spmm2_k(
    const float* __restrict__ y2, const int* __restrict__ cntg,
    const uint2* __restrict__ bins, float* __restrict__ out, int N) {
    const int lane = threadIdx.x & 63;
    const int f = lane & 31;
    const int sub = lane >> 5;
    const int row = (blockIdx.x * 256 + threadIdx.x) >> 6;
    if (row >= N) return;
    int cnt = cntg[row]; if (cnt > CAP) cnt = CAP;
    uint2 eg = make_uint2(0u, 0u);
    if (lane < cnt) eg = bins[(size_t)row * CAP + lane];
    float acc = 0.f;
    for (int j = 0; j < cnt; j += 4) {
        int s[2]; float w[2], v[2];
#pragma unroll
        for (int k = 0; k < 2; k++) {
            int idx = j + 2 * k + sub;
            bool ok = idx < cnt;
            int ss = __shfl((int)eg.x, idx);
            unsigned wb = (unsigned)__shfl((int)eg.y, idx);
            s[k] = ok ? ss : 0;
            w[k] = ok ? __uint_as_float(wb) : 0.f;
        }
#pragma unroll
        for (int k = 0; k < 2; k++) v[k] = y2[(size_t)s[k] * 32 + f];
#pragma unroll
        for (int k = 0; k < 2; k++) acc = fmaf(w[k], v[k], acc);
    }
    acc += __shfl_xor(acc, 32);
    if (sub == 0) {
        float* p = &out[(size_t)row * 32 + f];
        *p = *p + acc;
    }
}

__global__ __launch_bounds__(256) void ovf2_k(
    const float* __restrict__ y2, const int* __restrict__ ovfcnt,
    const int4* __restrict__ ovf, float* __restrict__ out) {
    int n = *ovfcnt; if (n > OVF_CAP) n = OVF_CAP;
    const int lane = threadIdx.x & 63;
    const int f = lane & 31;
    int wid = (blockIdx.x * 256 + threadIdx.x) >> 6;
    int nw = (gridDim.x * 256) >> 6;
    for (int i = wid; i < n; i += nw) {
        int4 t = ovf[i];
        if (lane < 32) {
            float w = __uint_as_float((unsigned)t.z);
            atomAdd(&out[(size_t)t.y * 32 + f], w * y2[(size_t)t.x * 32 + f]);
        }
    }
}

extern "C" void kernel_launch(void* const* d_in, const int* in_sizes, int n_in,
                              void* d_out, int out_size, void* d_ws, size_t ws_size,
                              hipStream_t stream) {
    const float* x      = (const float*)d_in[0];
    const float* ea     = (const float*)d_in[1];
    const float* W1rel  = (const float*)d_in[2];
    const float* b1     = (const float*)d_in[3];
    const float* W1root = (const float*)d_in[4];
    const float* gamma  = (const float*)d_in[5];
    const float* beta   = (const float*)d_in[6];
    const float* W2rel  = (const float*)d_in[7];
    const float* b2     = (const float*)d_in[8];
    const float* W2root = (const float*)d_in[9];
    const void*  ei     = d_in[10];

    const int N = in_sizes[0] / 64;   // 50000
    const int E = in_sizes[1];        // 800000
    const int nbg = (N + 63) / 64;    // gemm blocks (64 rows each)

    char* ws = (char*)d_ws;
    size_t off = 0;
    // --- zero-init region (contiguous) ---
    int*   cnt    = (int*)  (ws + off); off += ((size_t)N * 4 + 255) & ~255ull;
    int*   ovfcnt = (int*)  (ws + off); off += 256;
    float* bnsum  = (float*)(ws + off); off += 512;
    float* bnsq   = (float*)(ws + off); off += 512;
    const size_t zeroBytes = off;
    // --- no-init region ---
    float*  bnscale = (float*) (ws + off); off += 512;
    float*  bnshift = (float*) (ws + off); off += 512;
    float*  agg1    = (float*) (ws + off); off += (size_t)N * 64 * 4;    // 12.8 MB
    float*  h       = (float*) (ws + off); off += (size_t)N * 128 * 4;   // 25.6 MB
    float*  y2      = (float*) (ws + off); off += (size_t)N * 32 * 4;    // 6.4 MB
    uint2*  bins    = (uint2*) (ws + off); off += (size_t)N * CAP * 8;   // 12.8 MB
    int4*   ovf     = (int4*)  (ws + off); off += (size_t)OVF_CAP * 16;  // 2 MB
    __bf16* W1t     = (__bf16*)(ws + off); off += 128 * 128 * 2;
    __bf16* W2t     = (__bf16*)(ws + off); off += 64 * 128 * 2;

    hipMemsetAsync(ws, 0, zeroBytes, stream);
    fill_k<<<(E + 1023) / 1024, 256, 0, stream>>>(ea, ei, cnt, bins, ovfcnt, ovf, E, N);
    cvtw_k<<<96, 256, 0, stream>>>(W1rel, W1root, W2rel, W2root, W1t, W2t);
    const int rowBlocks = (N * 64 + 255) / 256;
    spmm1_k<<<rowBlocks, 256, 0, stream>>>(x, cnt, bins, agg1, N);
    ovf1_k<<<32, 256, 0, stream>>>(x, ovfcnt, ovf, agg1);
    gemm1_k<<<nbg, 256, 0, stream>>>(agg1, x, W1t, b1, h, bnsum, bnsq, N);
    bnfinal_k<<<1, 128, 0, stream>>>(bnsum, bnsq, gamma, beta, bnscale, bnshift, N);
    gemm2_k<<<nbg, 256, 0, stream>>>(h, bnscale, bnshift, W2t, b2, y2, (float*)d_out, N);
    spmm2_k<<<rowBlocks, 256, 0, stream>>>(y2, cnt, bins, (float*)d_out, N);
    ovf2_k<<<32, 256, 0, stream>>>(y2, ovfcnt, ovf, (float*)d_out);
}